// Round 9
// baseline (173.068 us; speedup 1.0000x reference)
//
#include <hip/hip_runtime.h>
#include <math.h>

#define HDIM 2048
#define NEXP 8
#define IDIM 16
#define N_EI 128

typedef __attribute__((ext_vector_type(8))) short bf16x8;
typedef __attribute__((ext_vector_type(4))) float f32x4;

// fp32 -> bf16 bits, round-to-nearest-even
static __device__ __forceinline__ short f2bf(float f) {
    union { float f; unsigned u; } v; v.f = f;
    unsigned r = v.u + 0x7fffu + ((v.u >> 16) & 1u);
    return (short)(r >> 16);
}

// ---------------------------------------------------------------------------
// K1 prep:
//   blocks [0, routerBlocks)    : router fp32 -> gate_ws[T][8]; fused x->bf16
//                                 (wave already holds the full x row)
//   blocks [routerBlocks, +256) : pack dw/uw -> b1p/b2p bf16 frag layout
//     b1p[(kb*128 + n)*8 + j]   = dw[n][kb*8 + j]
//     b2p[(k2b*2048 + h)*8 + j] = uw[e][h][i0 + j], e=k2b>>1, i0=(k2b&1)*8
// ---------------------------------------------------------------------------
__global__ __launch_bounds__(256) void prep_kernel(
    const float* __restrict__ x, const float* __restrict__ rw,
    const float* __restrict__ dw, const float* __restrict__ uw,
    float* __restrict__ gate_ws, short* __restrict__ b1p, short* __restrict__ b2p,
    short* __restrict__ x_bf, int T, int routerBlocks, int doXbf)
{
    const int bid = blockIdx.x;
    if (bid < routerBlocks) {
        const int wave = threadIdx.x >> 6, lane = threadIdx.x & 63;
        const int t = bid * 4 + wave;
        const float* __restrict__ xr = x + (size_t)t * HDIM;
        float4 xv[8];
        #pragma unroll
        for (int j = 0; j < 8; ++j) xv[j] = *(const float4*)(xr + j * 256 + lane * 4);

        // fused x -> bf16 store (coalesced 8B/lane per j)
        if (doXbf) {
            #pragma unroll
            for (int j = 0; j < 8; ++j) {
                unsigned lo = ((unsigned short)f2bf(xv[j].x)) | ((unsigned)(unsigned short)f2bf(xv[j].y) << 16);
                unsigned hi = ((unsigned short)f2bf(xv[j].z)) | ((unsigned)(unsigned short)f2bf(xv[j].w) << 16);
                *(uint2*)(x_bf + (size_t)t * HDIM + j * 256 + lane * 4) = make_uint2(lo, hi);
            }
        }

        float accv[NEXP];
        #pragma unroll
        for (int e = 0; e < NEXP; ++e) {
            const float* __restrict__ wr = rw + (size_t)e * HDIM;
            float acc = 0.f;
            #pragma unroll
            for (int j = 0; j < 8; ++j) {
                float4 wv = *(const float4*)(wr + j * 256 + lane * 4);
                acc += xv[j].x * wv.x + xv[j].y * wv.y + xv[j].z * wv.z + xv[j].w * wv.w;
            }
            accv[e] = acc;
        }
        #pragma unroll
        for (int s = 1; s < 64; s <<= 1) {
            #pragma unroll
            for (int e = 0; e < NEXP; ++e) accv[e] += __shfl_xor(accv[e], s);
        }
        if (lane == 0) {
            float m = accv[0];
            #pragma unroll
            for (int e = 1; e < NEXP; ++e) m = fmaxf(m, accv[e]);
            float w[NEXP], ssum = 0.f;
            #pragma unroll
            for (int e = 0; e < NEXP; ++e) { w[e] = expf(accv[e] - m); ssum += w[e]; }
            const float inv = 1.f / ssum;
            #pragma unroll
            for (int e = 0; e < NEXP; ++e) w[e] *= inv;
            int i1 = 0; float w1 = w[0];
            #pragma unroll
            for (int e = 1; e < NEXP; ++e) if (w[e] > w1) { w1 = w[e]; i1 = e; }
            int i2 = -1; float w2 = -1.f;
            #pragma unroll
            for (int e = 0; e < NEXP; ++e) if (e != i1 && w[e] > w2) { w2 = w[e]; i2 = e; }
            #pragma unroll
            for (int e = 0; e < NEXP; ++e)
                gate_ws[(size_t)t * NEXP + e] = (e == i1) ? w1 : ((e == i2) ? w2 : 0.f);
        }
    } else {
        const int id = (bid - routerBlocks) * 256 + threadIdx.x;   // 0..65535
        float4 v0, v1;
        short* dst;
        if (id < 32768) {            // b1p
            const int kb = id >> 7, n = id & 127;
            const float* __restrict__ src = dw + (size_t)n * HDIM + kb * 8;
            v0 = *(const float4*)(src);
            v1 = *(const float4*)(src + 4);
            dst = b1p + (size_t)id * 8;
        } else {                     // b2p
            const int id2 = id - 32768;
            const int k2b = id2 >> 11, h = id2 & 2047;
            const int e = k2b >> 1, i0 = (k2b & 1) * 8;
            const float* __restrict__ src = uw + ((size_t)e * HDIM + h) * IDIM + i0;
            v0 = *(const float4*)(src);
            v1 = *(const float4*)(src + 4);
            dst = b2p + (size_t)id2 * 8;
        }
        bf16x8 p;
        p[0] = f2bf(v0.x); p[1] = f2bf(v0.y); p[2] = f2bf(v0.z); p[3] = f2bf(v0.w);
        p[4] = f2bf(v1.x); p[5] = f2bf(v1.y); p[6] = f2bf(v1.z); p[7] = f2bf(v1.w);
        *(bf16x8*)dst = p;
    }
}

// ---------------------------------------------------------------------------
// K2 down: a[T,128] = silu(x @ dw^T) * gate, bf16. 16 tokens/block, 8 waves
// (4 nq x 2 kh, LDS reduce across kh). Operand-swapped MFMA: D[n][token].
// ---------------------------------------------------------------------------
template<bool XBF>
__global__ __launch_bounds__(512) void down_kernel(
    const float* __restrict__ x, const short* __restrict__ x_bf,
    const float* __restrict__ gate_ws, const short* __restrict__ b1p,
    short* __restrict__ a_gl, int T)
{
    __shared__ float h_part[16][132];   // 132 ≡ 4 (mod 32) dwords: conflict-free

    const int tid = threadIdx.x;
    const int w = tid >> 6, l = tid & 63;
    const int c = l & 15;               // token within frag
    const int kblk = l >> 4;
    const int t0 = blockIdx.x * 16;
    const int nq = w & 3, kh = w >> 2;
    const int n0 = nq * 32;

    f32x4 acc0 = {0,0,0,0}, acc1 = {0,0,0,0};
    const float* __restrict__ xr = x + (size_t)(t0 + c) * HDIM;
    const short* __restrict__ xb = x_bf + (size_t)(t0 + c) * HDIM;

    for (int s = 0; s < 32; ++s) {
        const int k0 = kh * 1024 + s * 32;
        const int ka = k0 + kblk * 8;
        bf16x8 xf;
        if (XBF) {
            xf = *(const bf16x8*)(xb + ka);
        } else {
            float4 a0 = *(const float4*)(xr + ka);
            float4 a1 = *(const float4*)(xr + ka + 4);
            xf[0]=f2bf(a0.x); xf[1]=f2bf(a0.y); xf[2]=f2bf(a0.z); xf[3]=f2bf(a0.w);
            xf[4]=f2bf(a1.x); xf[5]=f2bf(a1.y); xf[6]=f2bf(a1.z); xf[7]=f2bf(a1.w);
        }
        const short* __restrict__ bbase = b1p + ((size_t)(k0 >> 3) + kblk) * 1024;
        bf16x8 wf0 = *(const bf16x8*)(bbase + (n0 + c) * 8);
        bf16x8 wf1 = *(const bf16x8*)(bbase + (n0 + 16 + c) * 8);
        acc0 = __builtin_amdgcn_mfma_f32_16x16x32_bf16(wf0, xf, acc0, 0, 0, 0);
        acc1 = __builtin_amdgcn_mfma_f32_16x16x32_bf16(wf1, xf, acc1, 0, 0, 0);
    }

    if (kh == 1) {
        *(f32x4*)&h_part[c][n0 + kblk * 4]      = acc0;
        *(f32x4*)&h_part[c][n0 + 16 + kblk * 4] = acc1;
    }
    __syncthreads();
    if (kh == 0) {
        const f32x4 pa = *(const f32x4*)&h_part[c][n0 + kblk * 4];
        const f32x4 pb = *(const f32x4*)&h_part[c][n0 + 16 + kblk * 4];
        const float g0 = gate_ws[(size_t)(t0 + c) * NEXP + nq * 2];
        const float g1 = gate_ws[(size_t)(t0 + c) * NEXP + nq * 2 + 1];
        short r0[4], r1[4];
        #pragma unroll
        for (int r = 0; r < 4; ++r) {
            const float h0v = acc0[r] + pa[r];
            const float h1v = acc1[r] + pb[r];
            r0[r] = f2bf(h0v / (1.f + expf(-h0v)) * g0);
            r1[r] = f2bf(h1v / (1.f + expf(-h1v)) * g1);
        }
        short* __restrict__ arow = a_gl + (size_t)(t0 + c) * N_EI;
        *(uint2*)(arow + n0 + kblk * 4) =
            make_uint2(((unsigned short)r0[0]) | ((unsigned)(unsigned short)r0[1] << 16),
                       ((unsigned short)r0[2]) | ((unsigned)(unsigned short)r0[3] << 16));
        *(uint2*)(arow + n0 + 16 + kblk * 4) =
            make_uint2(((unsigned short)r1[0]) | ((unsigned)(unsigned short)r1[1] << 16),
                       ((unsigned short)r1[2]) | ((unsigned)(unsigned short)r1[3] << 16));
    }
}

// ---------------------------------------------------------------------------
// K3 up: out[T,2048] = a @ W2. Block = 32 tokens x 1024 h, 8 waves
// (2 t-halves x 4 h-quarters); wave = 16 tokens x 256 h = 64 MFMA.
// D[h][token]: lane holds 4 consecutive h for token c -> float4 stores.
// ---------------------------------------------------------------------------
__global__ __launch_bounds__(512) void up_kernel(
    const short* __restrict__ a_gl, const short* __restrict__ b2p,
    float* __restrict__ out, int T)
{
    const int tid = threadIdx.x;
    const int w = tid >> 6, l = tid & 63;
    const int c = l & 15;
    const int kblk = l >> 4;
    const int bid = blockIdx.x;
    const int tgrp = bid >> 1, bh = bid & 1;
    const int th = w >> 2, hq = w & 3;
    const int t0 = tgrp * 32 + th * 16;
    const int h0 = bh * 1024 + hq * 256;

    f32x4 acc[16];
    #pragma unroll
    for (int f = 0; f < 16; ++f) acc[f] = (f32x4){0,0,0,0};

    const short* __restrict__ arow = a_gl + (size_t)(t0 + c) * N_EI;
    for (int s = 0; s < 4; ++s) {
        bf16x8 af = *(const bf16x8*)(arow + s * 32 + kblk * 8);     // B-frag: col=token
        const short* __restrict__ bbase = b2p + ((size_t)(s * 4) + kblk) * 16384;
        #pragma unroll
        for (int f = 0; f < 16; ++f) {
            bf16x8 wfr = *(const bf16x8*)(bbase + (size_t)(h0 + f * 16 + c) * 8);  // A-frag: row=h
            acc[f] = __builtin_amdgcn_mfma_f32_16x16x32_bf16(wfr, af, acc[f], 0, 0, 0);
        }
    }
    float* __restrict__ orow = out + (size_t)(t0 + c) * HDIM;
    #pragma unroll
    for (int f = 0; f < 16; ++f)
        *(f32x4*)(orow + h0 + f * 16 + kblk * 4) = acc[f];
}

extern "C" void kernel_launch(void* const* d_in, const int* in_sizes, int n_in,
                              void* d_out, int out_size, void* d_ws, size_t ws_size,
                              hipStream_t stream) {
    const float* x  = (const float*)d_in[0];
    const float* rw = (const float*)d_in[1];
    const float* dw = (const float*)d_in[2];
    const float* uw = (const float*)d_in[3];
    float* out = (float*)d_out;
    const int T = in_sizes[0] / HDIM;   // 8192 tokens

    // ws layout: gate (256KB) | b1p (512KB) | b2p (512KB) | x_bf (32MB) | a_gl (2MB)
    char* wsb = (char*)d_ws;
    float* gate_ws = (float*)wsb;
    short* b1p  = (short*)(wsb + (size_t)T * NEXP * 4);
    short* b2p  = (short*)(wsb + (size_t)T * NEXP * 4 + 524288);
    short* x_bf = (short*)(wsb + (size_t)T * NEXP * 4 + 1048576);
    const size_t xbf_bytes = (size_t)T * HDIM * 2;

    const size_t need_full  = (size_t)T * NEXP * 4 + 1048576 + xbf_bytes + (size_t)T * N_EI * 2;
    const bool use_xbf = (ws_size >= need_full);
    short* a_gl = use_xbf
        ? (short*)(wsb + (size_t)T * NEXP * 4 + 1048576 + xbf_bytes)
        : (short*)(wsb + (size_t)T * NEXP * 4 + 1048576);   // reuse x_bf slot

    const int routerBlocks = T / 4;   // 2048
    prep_kernel<<<routerBlocks + 256, 256, 0, stream>>>(
        x, rw, dw, uw, gate_ws, b1p, b2p, x_bf, T, routerBlocks, use_xbf ? 1 : 0);

    if (use_xbf)
        down_kernel<true><<<T / 16, 512, 0, stream>>>(x, x_bf, gate_ws, b1p, a_gl, T);
    else
        down_kernel<false><<<T / 16, 512, 0, stream>>>(x, x_bf, gate_ws, b1p, a_gl, T);

    up_kernel<<<(T / 32) * 2, 512, 0, stream>>>(a_gl, b2p, out, T);
}